// Round 1
// baseline (10147.379 us; speedup 1.0000x reference)
//
#include <hip/hip_runtime.h>

// ---------------------------------------------------------------------------
// VariationalDropoutLSTM  (T=256, B=64, H=1024, L=2, fp32 in/out)
// Strategy: fp16 split-weight (hi+lo) MFMA GEMMs, fp16-hi activations.
//   gates = pre[t] + (h_{t-1} * mask_h[t]) @ Whh^T
//   pre   = input @ Wih^T + b_ih + b_hh   (input = x or h0_seq*mask_in)
// Layer-0 h_seq parked in out1 region; layer-1 overwrites out0/out1/out2.
// ---------------------------------------------------------------------------

#define T_STEPS 256
#define BATCH   64
#define HID     1024
#define G4      4096
#define OUTSZ   (T_STEPS * BATCH * HID)   // 16777216

typedef _Float16 half8 __attribute__((ext_vector_type(8)));
typedef _Float16 half4 __attribute__((ext_vector_type(4)));
typedef float    f32x4 __attribute__((ext_vector_type(4)));

__device__ __forceinline__ float sigm(float x) { return 1.0f / (1.0f + __expf(-x)); }

// ---------------------------------------------------------------------------
__global__ __launch_bounds__(256) void zero_ws(float* p, int n) {
    int i = blockIdx.x * 256 + threadIdx.x;
    if (i < n) p[i] = 0.0f;
}

// Split both weight tensors into fp16 hi/lo. 2*4096*1024 = 8388608 elems each,
// 4 per thread -> 2097152 threads.
__global__ __launch_bounds__(256) void split_w(
    const float* __restrict__ wih, const float* __restrict__ whh,
    _Float16* __restrict__ wih_hi, _Float16* __restrict__ wih_lo,
    _Float16* __restrict__ whh_hi, _Float16* __restrict__ whh_lo)
{
    int i = blockIdx.x * 256 + threadIdx.x;
    {
        float4 a = ((const float4*)wih)[i];
        half4 h, l;
        h[0] = (_Float16)a.x; l[0] = (_Float16)(a.x - (float)h[0]);
        h[1] = (_Float16)a.y; l[1] = (_Float16)(a.y - (float)h[1]);
        h[2] = (_Float16)a.z; l[2] = (_Float16)(a.z - (float)h[2]);
        h[3] = (_Float16)a.w; l[3] = (_Float16)(a.w - (float)h[3]);
        ((half4*)wih_hi)[i] = h; ((half4*)wih_lo)[i] = l;
    }
    {
        float4 a = ((const float4*)whh)[i];
        half4 h, l;
        h[0] = (_Float16)a.x; l[0] = (_Float16)(a.x - (float)h[0]);
        h[1] = (_Float16)a.y; l[1] = (_Float16)(a.y - (float)h[1]);
        h[2] = (_Float16)a.z; l[2] = (_Float16)(a.z - (float)h[2]);
        h[3] = (_Float16)a.w; l[3] = (_Float16)(a.w - (float)h[3]);
        ((half4*)whh_hi)[i] = h; ((half4*)whh_lo)[i] = l;
    }
}

// ---------------------------------------------------------------------------
// pre_gemm: preOut[row - row0][g] = dot(A[row]*mask[row], W[g]) + bih[g]+bhh[g]
// A: f32 [16384][1024]; W: fp16 hi/lo [4096][1024]; chunk of 4096 rows.
// 128x128 tile, BK=32, 256 thr (4 waves, 2x2), each wave 64x64 (4x4 frags).
__global__ __launch_bounds__(256) void pre_gemm(
    const float* __restrict__ A, const float* __restrict__ Amask, int row0,
    const _Float16* __restrict__ Bhi, const _Float16* __restrict__ Blo,
    const float* __restrict__ bih, const float* __restrict__ bhh,
    float* __restrict__ preOut)
{
    __shared__ _Float16 As [128][40];   // +8 pad: 80B stride, 16B aligned
    __shared__ _Float16 BsH[128][40];
    __shared__ _Float16 BsL[128][40];

    const int bm = blockIdx.x, bn = blockIdx.y;
    const int tid = threadIdx.x;
    const int wave = tid >> 6, lane = tid & 63;
    const int wm = wave & 1, wn = wave >> 1;
    const int lr = lane & 15, kq = lane >> 4;

    f32x4 acc[4][4] = {};

    const int mrow = tid >> 3;        // 0..31
    const int k4   = (tid & 7) * 4;   // 0..28
    const int nrow = tid >> 1;        // 0..127
    const int kb   = (tid & 1) * 16;  // 0 or 16

    for (int kk = 0; kk < 32; ++kk) {
        const int k0 = kk * 32;
        // ---- stage A (f32 -> fp16 hi only) ----
        #pragma unroll
        for (int mi = 0; mi < 4; ++mi) {
            const int m = mrow + mi * 32;
            const size_t gofs = (size_t)(row0 + bm * 128 + m) * 1024 + k0 + k4;
            float4 av = *(const float4*)(A + gofs);
            if (Amask) {
                float4 mv = *(const float4*)(Amask + gofs);
                av.x *= mv.x; av.y *= mv.y; av.z *= mv.z; av.w *= mv.w;
            }
            half4 hv;
            hv[0] = (_Float16)av.x; hv[1] = (_Float16)av.y;
            hv[2] = (_Float16)av.z; hv[3] = (_Float16)av.w;
            *(half4*)&As[m][k4] = hv;
        }
        // ---- stage B hi/lo ----
        {
            const size_t gofs = (size_t)(bn * 128 + nrow) * 1024 + k0 + kb;
            half8 b0 = *(const half8*)(Bhi + gofs);
            half8 b1 = *(const half8*)(Bhi + gofs + 8);
            *(half8*)&BsH[nrow][kb]     = b0;
            *(half8*)&BsH[nrow][kb + 8] = b1;
            half8 c0 = *(const half8*)(Blo + gofs);
            half8 c1 = *(const half8*)(Blo + gofs + 8);
            *(half8*)&BsL[nrow][kb]     = c0;
            *(half8*)&BsL[nrow][kb + 8] = c1;
        }
        __syncthreads();

        half8 af[4], bh[4], bl[4];
        #pragma unroll
        for (int i = 0; i < 4; ++i)
            af[i] = *(const half8*)&As[wm * 64 + i * 16 + lr][kq * 8];
        #pragma unroll
        for (int j = 0; j < 4; ++j) {
            bh[j] = *(const half8*)&BsH[wn * 64 + j * 16 + lr][kq * 8];
            bl[j] = *(const half8*)&BsL[wn * 64 + j * 16 + lr][kq * 8];
        }
        #pragma unroll
        for (int i = 0; i < 4; ++i)
            #pragma unroll
            for (int j = 0; j < 4; ++j) {
                acc[i][j] = __builtin_amdgcn_mfma_f32_16x16x32_f16(af[i], bl[j], acc[i][j], 0, 0, 0);
                acc[i][j] = __builtin_amdgcn_mfma_f32_16x16x32_f16(af[i], bh[j], acc[i][j], 0, 0, 0);
            }
        __syncthreads();
    }

    // epilogue: D col = lane&15, row = (lane>>4)*4 + reg
    #pragma unroll
    for (int j = 0; j < 4; ++j) {
        const int g = bn * 128 + wn * 64 + j * 16 + lr;
        const float bias = bih[g] + bhh[g];
        #pragma unroll
        for (int i = 0; i < 4; ++i) {
            const int rb = bm * 128 + wm * 64 + i * 16 + kq * 4;
            #pragma unroll
            for (int r = 0; r < 4; ++r)
                preOut[(size_t)(rb + r) * G4 + g] = acc[i][j][r] + bias;
        }
    }
}

// ---------------------------------------------------------------------------
// scan_step: one LSTM timestep.
// Grid 256 WGs: WG wg owns hidden cols j0 = wg*4 .. +4 (16 gate rows).
// GEMM: D[16 rows][64 batch] = Whh(rows) @ hm^T, fragments direct from global.
// Then LDS exchange + elementwise + writes.
__global__ __launch_bounds__(256) void scan_step(
    const float*    __restrict__ preT,    // [64][4096] for this t
    const _Float16* __restrict__ WhhHi,   // [4096][1024]
    const _Float16* __restrict__ WhhLo,
    const _Float16* __restrict__ hmIn,    // [64][1024]  h_{t-1}*mask_h[t]
    _Float16*       __restrict__ hmOut,   // [64][1024]  h_t*mask_h[t+1]
    const float*    __restrict__ maskNext,// mask_h[l][t+1] or nullptr
    float*          __restrict__ cbuf,    // [64][1024]
    float*          __restrict__ hOutA,   // h_t -> out region
    float*          __restrict__ hOutB,   // dup (layer 1) or nullptr
    float*          __restrict__ cOut)    // c_t (layer 1) or nullptr
{
    __shared__ float gl[16][68];

    const int wg = blockIdx.x;
    const int j0 = wg * 4;
    const int tid = threadIdx.x;
    const int wave = tid >> 6, lane = tid & 63;
    const int lr = lane & 15, kq = lane >> 4;

    // row_local rl = gate*4 + jj  (16 rows); global Whh row:
    const int grow = (lr >> 2) * HID + j0 + (lr & 3);
    const int bcol = wave * 16 + lr;   // batch column (each wave one 16-batch tile)

    f32x4 acc = {0.f, 0.f, 0.f, 0.f};
    const _Float16* wh = WhhHi + (size_t)grow * HID;
    const _Float16* wl = WhhLo + (size_t)grow * HID;
    const _Float16* hv = hmIn + (size_t)bcol * HID;

    #pragma unroll 4
    for (int kk = 0; kk < 32; ++kk) {
        const int k0 = kk * 32 + kq * 8;
        half8 ah = *(const half8*)(wh + k0);
        half8 al = *(const half8*)(wl + k0);
        half8 bb = *(const half8*)(hv + k0);
        acc = __builtin_amdgcn_mfma_f32_16x16x32_f16(al, bb, acc, 0, 0, 0);
        acc = __builtin_amdgcn_mfma_f32_16x16x32_f16(ah, bb, acc, 0, 0, 0);
    }

    #pragma unroll
    for (int r = 0; r < 4; ++r)
        gl[kq * 4 + r][wave * 16 + lr] = acc[r];
    __syncthreads();

    // elementwise: thread -> (jj = tid&3, b = tid>>2)
    const int jj = tid & 3;
    const int b  = tid >> 2;
    const int j  = j0 + jj;

    const float gi = gl[jj     ][b] + preT[(size_t)b * G4 + j];
    const float gf = gl[4  + jj][b] + preT[(size_t)b * G4 + HID + j];
    const float gg = gl[8  + jj][b] + preT[(size_t)b * G4 + 2 * HID + j];
    const float go = gl[12 + jj][b] + preT[(size_t)b * G4 + 3 * HID + j];

    const float si = sigm(gi);
    const float sf = sigm(gf);
    const float sg = tanhf(gg);
    const float so = sigm(go);

    const size_t bj = (size_t)b * HID + j;
    const float cprev = cbuf[bj];
    const float c = sf * cprev + si * sg;
    const float h = so * tanhf(c);
    cbuf[bj] = c;

    hOutA[bj] = h;
    if (hOutB) hOutB[bj] = h;
    if (cOut)  cOut[bj]  = c;
    if (maskNext) hmOut[bj] = (_Float16)(h * maskNext[bj]);
}

// ---------------------------------------------------------------------------
extern "C" void kernel_launch(void* const* d_in, const int* in_sizes, int n_in,
                              void* d_out, int out_size, void* d_ws, size_t ws_size,
                              hipStream_t stream)
{
    const float* x       = (const float*)d_in[0];
    const float* W_ih    = (const float*)d_in[1];
    const float* W_hh    = (const float*)d_in[2];
    const float* b_ih    = (const float*)d_in[3];
    const float* b_hh    = (const float*)d_in[4];
    const float* mask_h  = (const float*)d_in[5];
    const float* mask_in = (const float*)d_in[6];

    float* out0 = (float*)d_out;            // h_seq (layer 1)
    float* out1 = out0 + (size_t)OUTSZ;     // h_seq dup; holds layer-0 h_seq meanwhile
    float* out2 = out0 + 2 * (size_t)OUTSZ; // c_seq (layer 1)

    char* ws = (char*)d_ws;
    size_t off = 0;
    auto alloc = [&](size_t bytes) { void* p = ws + off; off += (bytes + 255) & ~(size_t)255; return p; };

    const size_t WELEM = (size_t)2 * G4 * HID;  // per split array (both layers)
    _Float16* wih_hi = (_Float16*)alloc(WELEM * 2);
    _Float16* wih_lo = (_Float16*)alloc(WELEM * 2);
    _Float16* whh_hi = (_Float16*)alloc(WELEM * 2);
    _Float16* whh_lo = (_Float16*)alloc(WELEM * 2);
    float*    pre    = (float*)alloc((size_t)64 * BATCH * G4 * 4);  // 67 MB chunk
    _Float16* hm     = (_Float16*)alloc((size_t)2 * BATCH * HID * 2); // ping-pong
    float*    cbuf   = (float*)alloc((size_t)BATCH * HID * 4);
    (void)ws_size; (void)in_sizes; (void)n_in; (void)out_size;

    split_w<<<8192, 256, 0, stream>>>(W_ih, W_hh, wih_hi, wih_lo, whh_hi, whh_lo);

    for (int l = 0; l < 2; ++l) {
        // zero hm ping-pong (2*65536 fp16 = 65536 f32) + cbuf (65536 f32)
        zero_ws<<<512, 256, 0, stream>>>((float*)hm, 131072);

        const float* Ain = l ? out1 : x;
        const float* Am  = l ? mask_in : nullptr;
        const _Float16* BH = wih_hi + (size_t)l * G4 * HID;
        const _Float16* BL = wih_lo + (size_t)l * G4 * HID;
        const _Float16* WH = whh_hi + (size_t)l * G4 * HID;
        const _Float16* WL = whh_lo + (size_t)l * G4 * HID;
        const float* bi = b_ih + l * G4;
        const float* bh = b_hh + l * G4;

        for (int c = 0; c < 4; ++c) {
            pre_gemm<<<dim3(32, 32), 256, 0, stream>>>(Ain, Am, c * 4096, BH, BL, bi, bh, pre);
            for (int tt = 0; tt < 64; ++tt) {
                const int t = c * 64 + tt;
                const float* mnext = (t < T_STEPS - 1)
                    ? mask_h + ((size_t)(l * T_STEPS + t + 1) * BATCH) * HID : nullptr;
                float* hA = (l ? out0 : out1) + (size_t)t * BATCH * HID;
                float* hB = l ? out1 + (size_t)t * BATCH * HID : nullptr;
                float* cO = l ? out2 + (size_t)t * BATCH * HID : nullptr;
                scan_step<<<256, 256, 0, stream>>>(
                    pre + (size_t)tt * BATCH * G4,
                    WH, WL,
                    hm + (size_t)(t & 1) * BATCH * HID,
                    hm + (size_t)((t + 1) & 1) * BATCH * HID,
                    mnext, cbuf, hA, hB, cO);
            }
        }
    }
}